// Round 4
// baseline (174.172 us; speedup 1.0000x reference)
//
#include <hip/hip_runtime.h>

#define B_ 16
#define C_ 306
#define CP_ 320
#define T_ 4000
#define M_ 128

typedef short bf16x8 __attribute__((ext_vector_type(8)));
typedef float f32x4 __attribute__((ext_vector_type(4)));

// ---------- Kernel A: gate MLP -> w_hi/w_lo [B][M][CP_] bf16 + scale[B][M] ----
// one block per (b, 4 m's); 320 threads (c = tid)
__global__ __launch_bounds__(320)
void gate_kernel(const float* __restrict__ positions,   // [B,C,2]
                 const float* __restrict__ target,      // [M,2]
                 const float* __restrict__ w1,          // [3,32]
                 const float* __restrict__ b1,          // [32]
                 const float* __restrict__ w2,          // [32]
                 const float* __restrict__ b2,          // [1]
                 unsigned short* __restrict__ w_hi,     // [B,M,CP_]
                 unsigned short* __restrict__ w_lo,     // [B,M,CP_]
                 float* __restrict__ scale) {           // [B,M]
    const int b  = blockIdx.x >> 5;     // 512 blocks = B * 32
    const int mg = blockIdx.x & 31;     // group of 4 m
    const int tid = threadIdx.x;        // 0..319

    __shared__ float s_w1[96], s_b1[32], s_w2[32];
    __shared__ float2 s_pos[C_];
    __shared__ float s_b2;
    __shared__ float s_tgt[8];
    __shared__ float s_part[5];

    if (tid < 96) s_w1[tid] = w1[tid];
    if (tid < 32) { s_b1[tid] = b1[tid]; s_w2[tid] = w2[tid]; }
    if (tid == 256) s_b2 = b2[0];
    if (tid < C_) s_pos[tid] = ((const float2*)positions)[b * C_ + tid];
    if (tid >= 312) s_tgt[tid - 312] = target[mg * 8 + (tid - 312)];
    __syncthreads();

    float px = 0.0f, py = 0.0f;
    if (tid < C_) { px = s_pos[tid].x; py = s_pos[tid].y; }

#pragma unroll
    for (int mi = 0; mi < 4; ++mi) {
        float w = 0.0f;
        if (tid < C_) {
            const float dx = px - s_tgt[mi * 2 + 0];
            const float dy = py - s_tgt[mi * 2 + 1];
            const float d2 = dx * dx + dy * dy;
            // s2 = exp(-3.125 d2); s1 = s2^4; s0 = s1^4
            const float s2 = __expf(-d2 * 3.125f);
            const float q  = s2 * s2;
            const float s1 = q * q;
            const float r  = s1 * s1;
            const float s0 = r * r;
            float acc = s_b2;
#pragma unroll
            for (int j = 0; j < 32; ++j) {
                float h = fmaf(s0, s_w1[j],
                          fmaf(s1, s_w1[32 + j],
                          fmaf(s2, s_w1[64 + j], s_b1[j])));
                acc = fmaf(fmaxf(h, 0.0f), s_w2[j], acc);
            }
            w = acc;
        }

        // block-wide sum
        float s = w;
#pragma unroll
        for (int off = 32; off > 0; off >>= 1) s += __shfl_down(s, off, 64);
        if ((tid & 63) == 0) s_part[tid >> 6] = s;
        __syncthreads();
        if (tid == 0) {
            float tot = s_part[0] + s_part[1] + s_part[2] + s_part[3] + s_part[4];
            scale[b * M_ + mg * 4 + mi] = 1.0f / (tot + 1e-8f);
        }
        __syncthreads();

        // split into bf16 hi (truncate) + lo
        const unsigned int u = __float_as_uint(w);
        const unsigned short h = (unsigned short)(u >> 16);
        const float lof = w - __uint_as_float(u & 0xffff0000u);
        const unsigned short l = (unsigned short)(__float_as_uint(lof) >> 16);
        const size_t off = (size_t)(b * M_ + mg * 4 + mi) * CP_ + tid;
        w_hi[off] = h;
        w_lo[off] = l;
    }
}

// ---------- Kernel B: MFMA GEMM  out[b][m][t] = scale[b][m] * sum_c w*x ------
// tile 64m x 64t, grid 63x2x16 = 2016 blocks (~6-8/CU), 4 waves of 32x32.
// BK=64, X tile in LDS (run-stride 260 words), W direct from global (L2).
// Register prefetch of next X step overlaps compute.
__global__ __launch_bounds__(256, 4)
void merge_gemm(const float* __restrict__ x,            // [B,C,T]
                const unsigned short* __restrict__ w_hi,// [B,M,CP_]
                const unsigned short* __restrict__ w_lo,
                const float* __restrict__ scale,        // [B,M]
                float* __restrict__ out) {              // [B,M,T]
    const int t0 = blockIdx.x * 64;
    const int m0 = blockIdx.y * 64;
    const int b  = blockIdx.z;
    const int tid  = threadIdx.x;
    const int lane = tid & 63;
    const int wv   = tid >> 6;
    const int tquad = lane >> 4;   // 0..3
    const int tsub  = lane & 15;   // 0..15

    // X tile: 8 runs (8 c each) x 64 t x 4 words; run stride 260 words (+4 skew)
    __shared__ __align__(16) unsigned int sXh[2076];
    __shared__ __align__(16) unsigned int sXl[2076];
    __shared__ __align__(16) float sScale[64];

    if (tid < 64) sScale[tid] = scale[b * M_ + m0 + tid];

    const float* xb = x + (size_t)b * C_ * T_;
    const unsigned short* whB = w_hi + (size_t)(b * M_ + m0) * CP_;
    const unsigned short* wlB = w_lo + (size_t)(b * M_ + m0) * CP_;

    const int mw = (wv & 1) * 32;    // wave m-origin (local)
    const int tw = (wv >> 1) * 32;   // wave t-origin (local)

    // staging assignment: lane owns c-quad pp (4 rows) x t-slot tq (4 t's)
    const int pp   = tid >> 4;          // 0..15
    const int tq   = tid & 15;          // 0..15
    const int runw = pp >> 1;           // 0..7
    const int w0   = (pp & 1) * 2;      // word offset in slot
    const float* xcol = xb + min(t0 + tq * 4, T_ - 4);

    f32x4 acc[2][2];
#pragma unroll
    for (int i = 0; i < 2; ++i)
#pragma unroll
        for (int j = 0; j < 2; ++j) acc[i][j] = (f32x4){0.f, 0.f, 0.f, 0.f};

    float4 rv[4];
    // prologue prefetch (step 0)
#pragma unroll
    for (int r = 0; r < 4; ++r) {
        const int c = min(pp * 4 + r, C_ - 1);
        rv[r] = *(const float4*)(xcol + (size_t)c * T_);
    }

    for (int step = 0; step < 5; ++step) {
        __syncthreads();   // LDS free (prev compute done); also covers sScale
        // ---- split fp32 -> bf16 hi/lo, pack c-pairs, write b64 to LDS
        {
            const float* f0 = (const float*)&rv[0];
            const float* f1 = (const float*)&rv[1];
            const float* f2 = (const float*)&rv[2];
            const float* f3 = (const float*)&rv[3];
            const int base = runw * 260 + tq * 16 + w0;
#pragma unroll
            for (int j = 0; j < 4; ++j) {
                const unsigned int u0 = __float_as_uint(f0[j]);
                const unsigned int u1 = __float_as_uint(f1[j]);
                const unsigned int u2 = __float_as_uint(f2[j]);
                const unsigned int u3 = __float_as_uint(f3[j]);
                const unsigned int h01 = (u0 >> 16) | (u1 & 0xffff0000u);
                const unsigned int h23 = (u2 >> 16) | (u3 & 0xffff0000u);
                const float l0 = f0[j] - __uint_as_float(u0 & 0xffff0000u);
                const float l1 = f1[j] - __uint_as_float(u1 & 0xffff0000u);
                const float l2 = f2[j] - __uint_as_float(u2 & 0xffff0000u);
                const float l3 = f3[j] - __uint_as_float(u3 & 0xffff0000u);
                const unsigned int l01 = (__float_as_uint(l0) >> 16) |
                                         (__float_as_uint(l1) & 0xffff0000u);
                const unsigned int l23 = (__float_as_uint(l2) >> 16) |
                                         (__float_as_uint(l3) & 0xffff0000u);
                *(uint2*)(sXh + base + j * 4) = make_uint2(h01, h23);
                *(uint2*)(sXl + base + j * 4) = make_uint2(l01, l23);
            }
        }
        __syncthreads();

        // ---- prefetch next step's X into registers (in flight during compute)
        if (step < 4) {
            const int c0n = (step + 1) * 64;
#pragma unroll
            for (int r = 0; r < 4; ++r) {
                const int c = min(c0n + pp * 4 + r, C_ - 1);
                rv[r] = *(const float4*)(xcol + (size_t)c * T_);
            }
        }

        // ---- compute: 2 substeps of K=32
        const int cbase = step * 64;
#pragma unroll
        for (int ks = 0; ks < 2; ++ks) {
            bf16x8 bh[2], bl[2];
#pragma unroll
            for (int i = 0; i < 2; ++i) {
                const int a = (ks * 4 + tquad) * 260 + (tw + i * 16 + tsub) * 4;
                bh[i] = *(const bf16x8*)(sXh + a);
                bl[i] = *(const bf16x8*)(sXl + a);
            }
#pragma unroll
            for (int mi = 0; mi < 2; ++mi) {
                const size_t woff = (size_t)(mw + mi * 16 + tsub) * CP_
                                  + cbase + ks * 32 + tquad * 8;
                const bf16x8 ah = *(const bf16x8*)(whB + woff);
                const bf16x8 al = *(const bf16x8*)(wlB + woff);
#pragma unroll
                for (int ti = 0; ti < 2; ++ti) {
                    acc[mi][ti] = __builtin_amdgcn_mfma_f32_16x16x32_bf16(
                        ah, bh[ti], acc[mi][ti], 0, 0, 0);
                    acc[mi][ti] = __builtin_amdgcn_mfma_f32_16x16x32_bf16(
                        ah, bl[ti], acc[mi][ti], 0, 0, 0);
                    acc[mi][ti] = __builtin_amdgcn_mfma_f32_16x16x32_bf16(
                        al, bh[ti], acc[mi][ti], 0, 0, 0);
                }
            }
        }
    }

    // ---- epilogue: fold scale, store (C/D: col = lane&15, row = quad*4+reg)
#pragma unroll
    for (int mi = 0; mi < 2; ++mi) {
        const int mloc = mw + mi * 16 + tquad * 4;
        const float4 sc = *(const float4*)(sScale + mloc);
        float* op = out + ((size_t)b * M_ + m0 + mloc) * T_;
#pragma unroll
        for (int ti = 0; ti < 2; ++ti) {
            const int tg = t0 + tw + ti * 16 + tsub;
            if (tg < T_) {
                op[(size_t)0 * T_ + tg] = acc[mi][ti][0] * sc.x;
                op[(size_t)1 * T_ + tg] = acc[mi][ti][1] * sc.y;
                op[(size_t)2 * T_ + tg] = acc[mi][ti][2] * sc.z;
                op[(size_t)3 * T_ + tg] = acc[mi][ti][3] * sc.w;
            }
        }
    }
}

extern "C" void kernel_launch(void* const* d_in, const int* in_sizes, int n_in,
                              void* d_out, int out_size, void* d_ws, size_t ws_size,
                              hipStream_t stream) {
    const float* x         = (const float*)d_in[0];
    const float* positions = (const float*)d_in[1];
    const float* target    = (const float*)d_in[2];
    const float* w1        = (const float*)d_in[3];
    const float* b1        = (const float*)d_in[4];
    const float* w2        = (const float*)d_in[5];
    const float* b2        = (const float*)d_in[6];
    float* out = (float*)d_out;

    unsigned short* w_hi = (unsigned short*)d_ws;                 // B*M*CP halfs
    unsigned short* w_lo = w_hi + (size_t)B_ * M_ * CP_;
    float* scale = (float*)(w_lo + (size_t)B_ * M_ * CP_);        // B*M floats

    gate_kernel<<<B_ * 32, 320, 0, stream>>>(positions, target, w1, b1, w2, b2,
                                             w_hi, w_lo, scale);

    dim3 grid((T_ + 63) / 64, 2, B_);
    merge_gemm<<<grid, 256, 0, stream>>>(x, w_hi, w_lo, scale, out);
}

// Round 5
// 150.463 us; speedup vs baseline: 1.1576x; 1.1576x over previous
//
#include <hip/hip_runtime.h>

#define B_ 16
#define C_ 306
#define CP_ 320
#define T_ 4000
#define M_ 128

typedef short bf16x8 __attribute__((ext_vector_type(8)));
typedef float f32x4 __attribute__((ext_vector_type(4)));

// W fragment array: [b][sub64(10)][q(4)][m(128)][hl(2)][slot(8)] u16
// c = sub64*32 + q*8 + slot ; per-b size = 10*4*128*16 = 81920 u16
#define WF_PER_B 81920

// ---------- Kernel A: gate MLP -> W in MFMA-fragment order + scale[B,M] ------
// one block per (b, 4 m's); 320 threads (c = tid)
__global__ __launch_bounds__(320)
void gate_kernel(const float* __restrict__ positions,   // [B,C,2]
                 const float* __restrict__ target,      // [M,2]
                 const float* __restrict__ w1,          // [3,32]
                 const float* __restrict__ b1,          // [32]
                 const float* __restrict__ w2,          // [32]
                 const float* __restrict__ b2,          // [1]
                 unsigned short* __restrict__ wf,       // fragment-order W
                 float* __restrict__ scale) {           // [B,M]
    const int b  = blockIdx.x >> 5;     // 512 blocks = B * 32
    const int mg = blockIdx.x & 31;     // group of 4 m
    const int tid = threadIdx.x;        // 0..319  (= c)

    __shared__ float s_w1[96], s_b1[32], s_w2[32];
    __shared__ float2 s_pos[C_];
    __shared__ float s_b2;
    __shared__ float s_tgt[8];
    __shared__ float s_part[5];
    // staged fragment chunks: [chunk(40)][mi(4)][hl(2)][slot(8)], stride 72 u16
    __shared__ unsigned short s_frag[40 * 72];

    if (tid < 96) s_w1[tid] = w1[tid];
    if (tid < 32) { s_b1[tid] = b1[tid]; s_w2[tid] = w2[tid]; }
    if (tid == 256) s_b2 = b2[0];
    if (tid < C_) s_pos[tid] = ((const float2*)positions)[b * C_ + tid];
    if (tid >= 312) s_tgt[tid - 312] = target[mg * 8 + (tid - 312)];
    __syncthreads();

    float px = 0.0f, py = 0.0f;
    if (tid < C_) { px = s_pos[tid].x; py = s_pos[tid].y; }

    const int chunk = tid >> 3;   // = (sub64*4 + q) for this c
    const int slot  = tid & 7;

#pragma unroll
    for (int mi = 0; mi < 4; ++mi) {
        float w = 0.0f;
        if (tid < C_) {
            const float dx = px - s_tgt[mi * 2 + 0];
            const float dy = py - s_tgt[mi * 2 + 1];
            const float d2 = dx * dx + dy * dy;
            const float s2 = __expf(-d2 * 3.125f);
            const float q  = s2 * s2;
            const float s1 = q * q;
            const float r  = s1 * s1;
            const float s0 = r * r;
            float acc = s_b2;
#pragma unroll
            for (int j = 0; j < 32; ++j) {
                float h = fmaf(s0, s_w1[j],
                          fmaf(s1, s_w1[32 + j],
                          fmaf(s2, s_w1[64 + j], s_b1[j])));
                acc = fmaf(fmaxf(h, 0.0f), s_w2[j], acc);
            }
            w = acc;
        }

        // block-wide sum over c
        float s = w;
#pragma unroll
        for (int off = 32; off > 0; off >>= 1) s += __shfl_down(s, off, 64);
        if ((tid & 63) == 0) s_part[tid >> 6] = s;
        __syncthreads();
        if (tid == 0) {
            float tot = s_part[0] + s_part[1] + s_part[2] + s_part[3] + s_part[4];
            scale[b * M_ + mg * 4 + mi] = 1.0f / (tot + 1e-8f);
        }
        __syncthreads();

        // split into bf16 hi (truncate) + lo, stage into fragment chunks
        const unsigned int u = __float_as_uint(w);
        const unsigned short h = (unsigned short)(u >> 16);
        const float lof = w - __uint_as_float(u & 0xffff0000u);
        const unsigned short l = (unsigned short)(__float_as_uint(lof) >> 16);
        s_frag[chunk * 72 + mi * 16 + 0 + slot] = h;
        s_frag[chunk * 72 + mi * 16 + 8 + slot] = l;
    }
    __syncthreads();

    // coalesced dump: thread -> (chunk = tid>>3, g = tid&7): 16 B each
    {
        const int ch = tid >> 3;       // 0..39
        const int g  = tid & 7;        // (mi = g>>1, hl = g&1)
        const uint4 v = *(const uint4*)(s_frag + ch * 72 + g * 8);
        // global u16 index: (chunk*128 + mg*4 + mi)*16 + hl*8
        unsigned short* dst = wf + (size_t)b * WF_PER_B
                            + (size_t)ch * 2048 + mg * 64 + g * 8;
        *(uint4*)dst = v;
    }
}

// ---------- Kernel B: MFMA GEMM  out[b][m][t] = scale[b][m] * sum_c w*x ------
// tile 128m x 128t, BK=64 (2 substeps of 32), 4 waves of 64x64.
// X: float4 loads -> split -> LDS [run(8)][TQ(32) stride 20w][tt(4)][pw(4)]
// W: direct from global in fragment order (coalesced dwordx4, L2-resident)
__global__ __launch_bounds__(256, 3)
void merge_gemm(const float* __restrict__ x,            // [B,C,T]
                const unsigned short* __restrict__ wf,  // fragment-order W
                const float* __restrict__ scale,        // [B,M]
                float* __restrict__ out) {              // [B,M,T]
    const int t0 = blockIdx.x * 128;
    const int b  = blockIdx.y;
    const int tid  = threadIdx.x;
    const int lane = tid & 63;
    const int wv   = tid >> 6;
    const int tquad = lane >> 4;   // 0..3
    const int tsub  = lane & 15;   // 0..15

    // run stride = 32*20 = 640 words; total 8*640 = 5120 words = 20 KB each
    __shared__ __align__(16) unsigned int sXh[5120];
    __shared__ __align__(16) unsigned int sXl[5120];
    __shared__ __align__(16) float sScale[M_];

    if (tid < M_) sScale[tid] = scale[b * M_ + tid];

    const float* xb = x + (size_t)b * C_ * T_;
    const unsigned short* wfB = wf + (size_t)b * WF_PER_B;

    f32x4 acc[4][4];
#pragma unroll
    for (int i = 0; i < 4; ++i)
#pragma unroll
        for (int j = 0; j < 4; ++j) acc[i][j] = (f32x4){0.f, 0.f, 0.f, 0.f};

    const int mw = (wv & 1) * 64;    // wave m-origin
    const int tw = (wv >> 1) * 64;   // wave t-origin

    // staging assignment
    const int p  = tid >> 4;         // c-pair base 0..15
    const int tq = tid & 15;         // t-quad base 0..15

    float4 rv[8];
    // prologue prefetch (step 0)
#pragma unroll
    for (int s = 0; s < 2; ++s) {
        const int TQ  = tq + 16 * s;
        const int tcl = min(t0 + TQ * 4, T_ - 4);
#pragma unroll
        for (int sub = 0; sub < 2; ++sub) {
            const int cp = p + 16 * sub;
            const int c  = 2 * cp;
            rv[(s * 2 + sub) * 2 + 0] =
                *(const float4*)(xb + (size_t)min(c, C_ - 1) * T_ + tcl);
            rv[(s * 2 + sub) * 2 + 1] =
                *(const float4*)(xb + (size_t)min(c + 1, C_ - 1) * T_ + tcl);
        }
    }

    for (int step = 0; step < 5; ++step) {
        __syncthreads();   // previous compute done; LDS reusable (covers sScale)

        // ---- split fp32 -> bf16 hi/lo, pack c-pairs, write to LDS
#pragma unroll
        for (int s = 0; s < 2; ++s) {
            const int TQ = tq + 16 * s;
#pragma unroll
            for (int sub = 0; sub < 2; ++sub) {
                const int cp  = p + 16 * sub;
                const int run = cp >> 2;
                const int pw  = cp & 3;
                const float* fa = (const float*)&rv[(s * 2 + sub) * 2 + 0];
                const float* fb = (const float*)&rv[(s * 2 + sub) * 2 + 1];
                const int base = run * 640 + TQ * 20 + pw;
#pragma unroll
                for (int tt = 0; tt < 4; ++tt) {
                    const unsigned int ua = __float_as_uint(fa[tt]);
                    const unsigned int ub = __float_as_uint(fb[tt]);
                    const float la = fa[tt] - __uint_as_float(ua & 0xffff0000u);
                    const float lb = fb[tt] - __uint_as_float(ub & 0xffff0000u);
                    sXh[base + tt * 4] = (ua >> 16) | (ub & 0xffff0000u);
                    sXl[base + tt * 4] = (__float_as_uint(la) >> 16) |
                                         (__float_as_uint(lb) & 0xffff0000u);
                }
            }
        }
        __syncthreads();

        // ---- prefetch next step's X (in flight during compute)
        if (step < 4) {
            const int c0n = (step + 1) * 64;
#pragma unroll
            for (int s = 0; s < 2; ++s) {
                const int TQ  = tq + 16 * s;
                const int tcl = min(t0 + TQ * 4, T_ - 4);
#pragma unroll
                for (int sub = 0; sub < 2; ++sub) {
                    const int c = c0n + 2 * (p + 16 * sub);
                    rv[(s * 2 + sub) * 2 + 0] =
                        *(const float4*)(xb + (size_t)min(c, C_ - 1) * T_ + tcl);
                    rv[(s * 2 + sub) * 2 + 1] =
                        *(const float4*)(xb + (size_t)min(c + 1, C_ - 1) * T_ + tcl);
                }
            }
        }

        // ---- compute: 2 substeps of K=32
#pragma unroll
        for (int ks = 0; ks < 2; ++ks) {
            const int sub64 = step * 2 + ks;
            const int runb  = ks * 4 + tquad;

            bf16x8 bh[4], bl[4];
#pragma unroll
            for (int i = 0; i < 4; ++i) {
                const int t = tw + i * 16 + tsub;
                const int a = runb * 640 + (t >> 2) * 20 + (t & 3) * 4;
                bh[i] = *(const bf16x8*)(sXh + a);
                bl[i] = *(const bf16x8*)(sXl + a);
            }
#pragma unroll
            for (int mi = 0; mi < 4; ++mi) {
                const size_t aoff = ((size_t)(sub64 * 4 + tquad) * 128
                                   + (mw + mi * 16 + tsub)) * 16;
                const bf16x8 ah = *(const bf16x8*)(wfB + aoff);
                const bf16x8 al = *(const bf16x8*)(wfB + aoff + 8);
#pragma unroll
                for (int ti = 0; ti < 4; ++ti) {
                    acc[mi][ti] = __builtin_amdgcn_mfma_f32_16x16x32_bf16(
                        ah, bh[ti], acc[mi][ti], 0, 0, 0);
                    acc[mi][ti] = __builtin_amdgcn_mfma_f32_16x16x32_bf16(
                        ah, bl[ti], acc[mi][ti], 0, 0, 0);
                    acc[mi][ti] = __builtin_amdgcn_mfma_f32_16x16x32_bf16(
                        al, bh[ti], acc[mi][ti], 0, 0, 0);
                }
            }
        }
    }

    // ---- epilogue: fold scale, store (C/D: col = lane&15, row = quad*4+reg)
#pragma unroll
    for (int mi = 0; mi < 4; ++mi) {
        const int mbase = mw + mi * 16 + tquad * 4;
        const float4 sc = *(const float4*)(sScale + mbase);
        float* op = out + ((size_t)b * M_ + mbase) * T_;
#pragma unroll
        for (int ti = 0; ti < 4; ++ti) {
            const int tg = t0 + tw + ti * 16 + tsub;
            if (tg < T_) {
                op[(size_t)0 * T_ + tg] = acc[mi][ti][0] * sc.x;
                op[(size_t)1 * T_ + tg] = acc[mi][ti][1] * sc.y;
                op[(size_t)2 * T_ + tg] = acc[mi][ti][2] * sc.z;
                op[(size_t)3 * T_ + tg] = acc[mi][ti][3] * sc.w;
            }
        }
    }
}

extern "C" void kernel_launch(void* const* d_in, const int* in_sizes, int n_in,
                              void* d_out, int out_size, void* d_ws, size_t ws_size,
                              hipStream_t stream) {
    const float* x         = (const float*)d_in[0];
    const float* positions = (const float*)d_in[1];
    const float* target    = (const float*)d_in[2];
    const float* w1        = (const float*)d_in[3];
    const float* b1        = (const float*)d_in[4];
    const float* w2        = (const float*)d_in[5];
    const float* b2        = (const float*)d_in[6];
    float* out = (float*)d_out;

    float* scale = (float*)d_ws;                          // B*M floats (8 KB)
    unsigned short* wf = (unsigned short*)(scale + B_ * M_); // 16*81920 u16

    gate_kernel<<<B_ * 32, 320, 0, stream>>>(positions, target, w1, b1, w2, b2,
                                             wf, scale);

    dim3 grid((T_ + 127) / 128, B_);
    merge_gemm<<<grid, 256, 0, stream>>>(x, wf, scale, out);
}

// Round 6
// 148.392 us; speedup vs baseline: 1.1737x; 1.0140x over previous
//
#include <hip/hip_runtime.h>

#define B_ 16
#define C_ 306
#define T_ 4000
#define M_ 128

typedef short bf16x8 __attribute__((ext_vector_type(8)));
typedef float f32x4 __attribute__((ext_vector_type(4)));

// W fragment array: [b][chunk(40)][m(128)][hl(2)][slot(8)] u16
// chunk = c>>3 (c = chunk*8 + slot); per-b size = 40*128*16 = 81920 u16
#define WF_PER_B 81920

// ---------- Kernel A: gate MLP -> W in MFMA-fragment order + scale[B,M] ------
// one block per (b, 4 m's); 320 threads (c = tid)
__global__ __launch_bounds__(320)
void gate_kernel(const float* __restrict__ positions,   // [B,C,2]
                 const float* __restrict__ target,      // [M,2]
                 const float* __restrict__ w1,          // [3,32]
                 const float* __restrict__ b1,          // [32]
                 const float* __restrict__ w2,          // [32]
                 const float* __restrict__ b2,          // [1]
                 unsigned short* __restrict__ wf,       // fragment-order W
                 float* __restrict__ scale) {           // [B,M]
    const int b  = blockIdx.x >> 5;     // 512 blocks = B * 32
    const int mg = blockIdx.x & 31;     // group of 4 m
    const int tid = threadIdx.x;        // 0..319  (= c)

    __shared__ float s_w1[96], s_b1[32], s_w2[32];
    __shared__ float s_b2;
    __shared__ float s_tgt[8];
    __shared__ float s_part[4][5];
    // staged fragment chunks: [chunk(40)][mi(4)][hl(2)][slot(8)], stride 72 u16
    __shared__ unsigned short s_frag[40 * 72];

    if (tid < 96) s_w1[tid] = w1[tid];
    if (tid < 32) { s_b1[tid] = b1[tid]; s_w2[tid] = w2[tid]; }
    if (tid == 256) s_b2 = b2[0];
    if (tid >= 312) s_tgt[tid - 312] = target[mg * 8 + (tid - 312)];
    __syncthreads();

    float px = 0.0f, py = 0.0f;
    if (tid < C_) {
        px = positions[(b * C_ + tid) * 2 + 0];
        py = positions[(b * C_ + tid) * 2 + 1];
    }

    float wv_[4];
#pragma unroll
    for (int mi = 0; mi < 4; ++mi) {
        float w = 0.0f;
        if (tid < C_) {
            const float dx = px - s_tgt[mi * 2 + 0];
            const float dy = py - s_tgt[mi * 2 + 1];
            const float d2 = dx * dx + dy * dy;
            const float s2 = __expf(-d2 * 3.125f);
            const float q  = s2 * s2;
            const float s1 = q * q;
            const float r  = s1 * s1;
            const float s0 = r * r;
            float acc = s_b2;
#pragma unroll
            for (int j = 0; j < 32; ++j) {
                float h = fmaf(s0, s_w1[j],
                          fmaf(s1, s_w1[32 + j],
                          fmaf(s2, s_w1[64 + j], s_b1[j])));
                acc = fmaf(fmaxf(h, 0.0f), s_w2[j], acc);
            }
            w = acc;
        }
        wv_[mi] = w;
    }

    // wave-level reductions, one LDS pass
#pragma unroll
    for (int mi = 0; mi < 4; ++mi) {
        float s = wv_[mi];
#pragma unroll
        for (int off = 32; off > 0; off >>= 1) s += __shfl_down(s, off, 64);
        if ((tid & 63) == 0) s_part[mi][tid >> 6] = s;
    }

    // split into bf16 hi/lo, stage fragment chunks
    const int chunk = tid >> 3;   // 0..39
    const int slot  = tid & 7;
#pragma unroll
    for (int mi = 0; mi < 4; ++mi) {
        const float w = wv_[mi];
        const unsigned int u = __float_as_uint(w);
        const unsigned short h = (unsigned short)(u >> 16);
        const float lof = w - __uint_as_float(u & 0xffff0000u);
        const unsigned short l = (unsigned short)(__float_as_uint(lof) >> 16);
        s_frag[chunk * 72 + mi * 16 + 0 + slot] = h;
        s_frag[chunk * 72 + mi * 16 + 8 + slot] = l;
    }
    __syncthreads();

    if (tid < 4) {
        float tot = s_part[tid][0] + s_part[tid][1] + s_part[tid][2]
                  + s_part[tid][3] + s_part[tid][4];
        scale[b * M_ + mg * 4 + tid] = 1.0f / (tot + 1e-8f);
    }

    // coalesced dump: thread -> (chunk = tid>>3, g = tid&7): 16 B each
    {
        const int ch = tid >> 3;       // 0..39
        const int g  = tid & 7;        // (mi = g>>1, hl = g&1)
        const uint4 v = *(const uint4*)(s_frag + ch * 72 + g * 8);
        unsigned short* dst = wf + (size_t)b * WF_PER_B
                            + (size_t)ch * 2048 + mg * 64 + g * 8;
        *(uint4*)dst = v;
    }
}

// ---------- Kernel B: MFMA GEMM  out[b][m][t] = scale[b][m] * sum_c w*x ------
// tile 128m x 128t, 512 threads (8 waves of 64m x 32t), BK=32,
// double-buffered LDS, ONE barrier per K-step. W direct from global (L2,
// fragment order); X: float4 loads -> split bf16 hi/lo -> LDS.
__global__ __launch_bounds__(512, 4)
void merge_gemm(const float* __restrict__ x,            // [B,C,T]
                const unsigned short* __restrict__ wf,  // fragment-order W
                const float* __restrict__ scale,        // [B,M]
                float* __restrict__ out) {              // [B,M,T]
    const int t0 = blockIdx.x * 128;
    const int b  = blockIdx.y;
    const int tid  = threadIdx.x;     // 0..511
    const int lane = tid & 63;
    const int wv   = tid >> 6;        // 0..7
    const int tquad = lane >> 4;      // 0..3
    const int tsub  = lane & 15;      // 0..15

    // per buffer: [run(4)][TQ(32) stride 20w] = 2560 words = 10 KB
    __shared__ __align__(16) unsigned int sXh[2][2560];
    __shared__ __align__(16) unsigned int sXl[2][2560];
    __shared__ __align__(16) float sScale[M_];

    if (tid < M_) sScale[tid] = scale[b * M_ + tid];

    const float* xb = x + (size_t)b * C_ * T_;
    const unsigned short* wfB = wf + (size_t)b * WF_PER_B;

    f32x4 acc[4][2];
#pragma unroll
    for (int i = 0; i < 4; ++i)
#pragma unroll
        for (int j = 0; j < 2; ++j) acc[i][j] = (f32x4){0.f, 0.f, 0.f, 0.f};

    const int mw = (wv & 1) * 64;    // wave m-origin
    const int tw = (wv >> 1) * 32;   // wave t-origin

    // staging: thread owns c-pair p (c = 2p, 2p+1) at t-quad TQ
    const int p  = tid >> 5;         // 0..15
    const int TQ = tid & 31;         // 0..31
    const int run = p >> 2;
    const int pw  = p & 3;
    const float* xcol = xb + min(t0 + TQ * 4, T_ - 4);
    const int lbase = run * 640 + TQ * 20 + pw;

    float4 cur0 = *(const float4*)(xcol + (size_t)min(2 * p,     C_ - 1) * T_);
    float4 cur1 = *(const float4*)(xcol + (size_t)min(2 * p + 1, C_ - 1) * T_);

    for (int step = 0; step < 10; ++step) {
        // prefetch next step's x (in flight through the pack phase)
        float4 nxt0, nxt1;
        if (step < 9) {
            const int c = (step + 1) * 32 + 2 * p;
            nxt0 = *(const float4*)(xcol + (size_t)min(c,     C_ - 1) * T_);
            nxt1 = *(const float4*)(xcol + (size_t)min(c + 1, C_ - 1) * T_);
        }

        // pack cur -> buf[step&1]
        {
            unsigned int* Dh = &sXh[step & 1][0];
            unsigned int* Dl = &sXl[step & 1][0];
            const float* fa = (const float*)&cur0;
            const float* fb = (const float*)&cur1;
#pragma unroll
            for (int tt = 0; tt < 4; ++tt) {
                const unsigned int ua = __float_as_uint(fa[tt]);
                const unsigned int ub = __float_as_uint(fb[tt]);
                const float la = fa[tt] - __uint_as_float(ua & 0xffff0000u);
                const float lb = fb[tt] - __uint_as_float(ub & 0xffff0000u);
                Dh[lbase + tt * 4] = (ua >> 16) | (ub & 0xffff0000u);
                Dl[lbase + tt * 4] = (__float_as_uint(la) >> 16) |
                                     (__float_as_uint(lb) & 0xffff0000u);
            }
        }
        __syncthreads();   // single barrier per step (dbuf makes it sufficient)

        // compute from buf[step&1]
        {
            const unsigned int* Sh = &sXh[step & 1][0];
            const unsigned int* Sl = &sXl[step & 1][0];
            bf16x8 bh[2], bl[2];
#pragma unroll
            for (int i = 0; i < 2; ++i) {
                const int t = tw + i * 16 + tsub;
                const int a = tquad * 640 + (t >> 2) * 20 + (t & 3) * 4;
                bh[i] = *(const bf16x8*)(Sh + a);
                bl[i] = *(const bf16x8*)(Sl + a);
            }
#pragma unroll
            for (int mi = 0; mi < 4; ++mi) {
                const size_t aoff = ((size_t)(step * 4 + tquad) * 128
                                   + (mw + mi * 16 + tsub)) * 16;
                const bf16x8 ah = *(const bf16x8*)(wfB + aoff);
                const bf16x8 al = *(const bf16x8*)(wfB + aoff + 8);
#pragma unroll
                for (int ti = 0; ti < 2; ++ti) {
                    acc[mi][ti] = __builtin_amdgcn_mfma_f32_16x16x32_bf16(
                        ah, bh[ti], acc[mi][ti], 0, 0, 0);
                    acc[mi][ti] = __builtin_amdgcn_mfma_f32_16x16x32_bf16(
                        ah, bl[ti], acc[mi][ti], 0, 0, 0);
                    acc[mi][ti] = __builtin_amdgcn_mfma_f32_16x16x32_bf16(
                        al, bh[ti], acc[mi][ti], 0, 0, 0);
                }
            }
        }
        cur0 = nxt0;
        cur1 = nxt1;
    }

    // ---- epilogue: fold scale, store (C/D: col = lane&15, row = quad*4+reg)
#pragma unroll
    for (int mi = 0; mi < 4; ++mi) {
        const int mbase = mw + mi * 16 + tquad * 4;
        const float4 sc = *(const float4*)(sScale + mbase);
        float* op = out + ((size_t)b * M_ + mbase) * T_;
#pragma unroll
        for (int ti = 0; ti < 2; ++ti) {
            const int tg = t0 + tw + ti * 16 + tsub;
            if (tg < T_) {
                op[(size_t)0 * T_ + tg] = acc[mi][ti][0] * sc.x;
                op[(size_t)1 * T_ + tg] = acc[mi][ti][1] * sc.y;
                op[(size_t)2 * T_ + tg] = acc[mi][ti][2] * sc.z;
                op[(size_t)3 * T_ + tg] = acc[mi][ti][3] * sc.w;
            }
        }
    }
}

extern "C" void kernel_launch(void* const* d_in, const int* in_sizes, int n_in,
                              void* d_out, int out_size, void* d_ws, size_t ws_size,
                              hipStream_t stream) {
    const float* x         = (const float*)d_in[0];
    const float* positions = (const float*)d_in[1];
    const float* target    = (const float*)d_in[2];
    const float* w1        = (const float*)d_in[3];
    const float* b1        = (const float*)d_in[4];
    const float* w2        = (const float*)d_in[5];
    const float* b2        = (const float*)d_in[6];
    float* out = (float*)d_out;

    float* scale = (float*)d_ws;                             // B*M floats
    unsigned short* wf = (unsigned short*)(scale + B_ * M_); // 16*81920 u16

    gate_kernel<<<B_ * 32, 320, 0, stream>>>(positions, target, w1, b1, w2, b2,
                                             wf, scale);

    dim3 grid((T_ + 127) / 128, B_);
    merge_gemm<<<grid, 512, 0, stream>>>(x, wf, scale, out);
}

// Round 7
// 143.375 us; speedup vs baseline: 1.2148x; 1.0350x over previous
//
#include <hip/hip_runtime.h>

#define B_ 16
#define C_ 306
#define T_ 4000
#define M_ 128

typedef short bf16x8 __attribute__((ext_vector_type(8)));
typedef float f32x4 __attribute__((ext_vector_type(4)));

// W fragment array: [b][chunk(40)][m(128)][hl(2)][slot(8)] u16
// chunk = c>>3 (c = chunk*8 + slot); per-b size = 40*128*16 = 81920 u16
#define WF_PER_B 81920

// ---------- Kernel A: gate MLP -> W in MFMA-fragment order + scale[B,M] ------
__global__ __launch_bounds__(320)
void gate_kernel(const float* __restrict__ positions,   // [B,C,2]
                 const float* __restrict__ target,      // [M,2]
                 const float* __restrict__ w1,          // [3,32]
                 const float* __restrict__ b1,          // [32]
                 const float* __restrict__ w2,          // [32]
                 const float* __restrict__ b2,          // [1]
                 unsigned short* __restrict__ wf,       // fragment-order W
                 float* __restrict__ scale) {           // [B,M]
    const int b  = blockIdx.x >> 5;     // 512 blocks = B * 32
    const int mg = blockIdx.x & 31;     // group of 4 m
    const int tid = threadIdx.x;        // 0..319  (= c)

    __shared__ float s_w1[96], s_b1[32], s_w2[32];
    __shared__ float s_b2;
    __shared__ float s_tgt[8];
    __shared__ float s_part[4][5];
    __shared__ unsigned short s_frag[40 * 72];

    if (tid < 96) s_w1[tid] = w1[tid];
    if (tid < 32) { s_b1[tid] = b1[tid]; s_w2[tid] = w2[tid]; }
    if (tid == 256) s_b2 = b2[0];
    if (tid >= 312) s_tgt[tid - 312] = target[mg * 8 + (tid - 312)];
    __syncthreads();

    float px = 0.0f, py = 0.0f;
    if (tid < C_) {
        px = positions[(b * C_ + tid) * 2 + 0];
        py = positions[(b * C_ + tid) * 2 + 1];
    }

    float wv_[4];
#pragma unroll
    for (int mi = 0; mi < 4; ++mi) {
        float w = 0.0f;
        if (tid < C_) {
            const float dx = px - s_tgt[mi * 2 + 0];
            const float dy = py - s_tgt[mi * 2 + 1];
            const float d2 = dx * dx + dy * dy;
            const float s2 = __expf(-d2 * 3.125f);
            const float q  = s2 * s2;
            const float s1 = q * q;
            const float r  = s1 * s1;
            const float s0 = r * r;
            float acc = s_b2;
#pragma unroll
            for (int j = 0; j < 32; ++j) {
                float h = fmaf(s0, s_w1[j],
                          fmaf(s1, s_w1[32 + j],
                          fmaf(s2, s_w1[64 + j], s_b1[j])));
                acc = fmaf(fmaxf(h, 0.0f), s_w2[j], acc);
            }
            w = acc;
        }
        wv_[mi] = w;
    }

#pragma unroll
    for (int mi = 0; mi < 4; ++mi) {
        float s = wv_[mi];
#pragma unroll
        for (int off = 32; off > 0; off >>= 1) s += __shfl_down(s, off, 64);
        if ((tid & 63) == 0) s_part[mi][tid >> 6] = s;
    }

    const int chunk = tid >> 3;   // 0..39
    const int slot  = tid & 7;
#pragma unroll
    for (int mi = 0; mi < 4; ++mi) {
        const float w = wv_[mi];
        const unsigned int u = __float_as_uint(w);
        const unsigned short h = (unsigned short)(u >> 16);
        const float lof = w - __uint_as_float(u & 0xffff0000u);
        const unsigned short l = (unsigned short)(__float_as_uint(lof) >> 16);
        s_frag[chunk * 72 + mi * 16 + 0 + slot] = h;
        s_frag[chunk * 72 + mi * 16 + 8 + slot] = l;
    }
    __syncthreads();

    if (tid < 4) {
        float tot = s_part[tid][0] + s_part[tid][1] + s_part[tid][2]
                  + s_part[tid][3] + s_part[tid][4];
        scale[b * M_ + mg * 4 + tid] = 1.0f / (tot + 1e-8f);
    }

    {
        const int ch = tid >> 3;       // 0..39
        const int g  = tid & 7;        // (mi = g>>1, hl = g&1)
        const uint4 v = *(const uint4*)(s_frag + ch * 72 + g * 8);
        unsigned short* dst = wf + (size_t)b * WF_PER_B
                            + (size_t)ch * 2048 + mg * 64 + g * 8;
        *(uint4*)dst = v;
    }
}

// ---------- Kernel B: MFMA GEMM  out[b][m][t] = scale[b][m] * sum_c w*x ------
// 256 threads, tile 128m x 128t, 4 waves of 64x64, BK=32, 10 steps fully
// unrolled. Double-buffered X LDS (1 barrier/step). W fragments AND x are
// register-prefetched one full K-step ahead -> no load->use latency exposure.
#define RUNSTRIDE 648   // 32 TQ * 20 words + 8 skew (mod 32 = 8)

__global__ __launch_bounds__(256, 2)
void merge_gemm(const float* __restrict__ x,            // [B,C,T]
                const unsigned short* __restrict__ wf,  // fragment-order W
                const float* __restrict__ scale,        // [B,M]
                float* __restrict__ out) {              // [B,M,T]
    const int t0 = blockIdx.x * 128;
    const int b  = blockIdx.y;
    const int tid  = threadIdx.x;     // 0..255
    const int lane = tid & 63;
    const int wv   = tid >> 6;        // 0..3
    const int tquad = lane >> 4;      // 0..3
    const int tsub  = lane & 15;      // 0..15

    __shared__ __align__(16) unsigned int sXh[2][4 * RUNSTRIDE];
    __shared__ __align__(16) unsigned int sXl[2][4 * RUNSTRIDE];
    __shared__ __align__(16) float sScale[M_];

    if (tid < M_) sScale[tid] = scale[b * M_ + tid];

    const float* xb = x + (size_t)b * C_ * T_;
    const unsigned short* wfB = wf + (size_t)b * WF_PER_B;

    f32x4 acc[4][4];
#pragma unroll
    for (int i = 0; i < 4; ++i)
#pragma unroll
        for (int j = 0; j < 4; ++j) acc[i][j] = (f32x4){0.f, 0.f, 0.f, 0.f};

    const int mw = (wv & 1) * 64;    // wave m-origin
    const int tw = (wv >> 1) * 64;   // wave t-origin

    // staging: thread owns c-pairs {cpB, cpB+8} at t-quad TQ
    const int cpB = tid >> 5;        // 0..7
    const int TQ  = tid & 31;        // 0..31
    const float* xcol = xb + min(t0 + TQ * 4, T_ - 4);

    // ---- helpers as lambdas (inlined) ----
    auto loadX = [&](int k, float4* xv) {
#pragma unroll
        for (int sub = 0; sub < 2; ++sub) {
            const int cp = cpB + 8 * sub;
            const int c  = k * 32 + 2 * cp;
            xv[sub * 2 + 0] = *(const float4*)(xcol + (size_t)min(c,     C_ - 1) * T_);
            xv[sub * 2 + 1] = *(const float4*)(xcol + (size_t)min(c + 1, C_ - 1) * T_);
        }
    };
    auto loadW = [&](int k, bf16x8* ah, bf16x8* al) {
#pragma unroll
        for (int mi = 0; mi < 4; ++mi) {
            const size_t aoff = ((size_t)(k * 4 + tquad) * 128
                               + (mw + mi * 16 + tsub)) * 16;
            ah[mi] = *(const bf16x8*)(wfB + aoff);
            al[mi] = *(const bf16x8*)(wfB + aoff + 8);
        }
    };
    auto packX = [&](const float4* xv, unsigned int* Dh, unsigned int* Dl) {
#pragma unroll
        for (int sub = 0; sub < 2; ++sub) {
            const int cp  = cpB + 8 * sub;
            const int run = cp >> 2;
            const int pw  = cp & 3;
            const float* fa = (const float*)&xv[sub * 2 + 0];
            const float* fb = (const float*)&xv[sub * 2 + 1];
            const int base = run * RUNSTRIDE + TQ * 20 + pw;
#pragma unroll
            for (int tt = 0; tt < 4; ++tt) {
                const unsigned int ua = __float_as_uint(fa[tt]);
                const unsigned int ub = __float_as_uint(fb[tt]);
                const float la = fa[tt] - __uint_as_float(ua & 0xffff0000u);
                const float lb = fb[tt] - __uint_as_float(ub & 0xffff0000u);
                Dh[base + tt * 4] = (ua >> 16) | (ub & 0xffff0000u);
                Dl[base + tt * 4] = (__float_as_uint(la) >> 16) |
                                    (__float_as_uint(lb) & 0xffff0000u);
            }
        }
    };

    // ---- prologue: stage step 0 ----
    bf16x8 ah[4], al[4];
    {
        float4 xv[4];
        loadX(0, xv);
        loadW(0, ah, al);
        packX(xv, &sXh[0][0], &sXl[0][0]);
    }
    __syncthreads();

#pragma unroll
    for (int k = 0; k < 10; ++k) {
        // issue next step's loads first (consumed after the next barrier)
        float4 xn[4];
        bf16x8 ahn[4], aln[4];
        if (k < 9) {
            loadX(k + 1, xn);
            loadW(k + 1, ahn, aln);
        }

        // B fragments from LDS buf[k&1]
        const unsigned int* Sh = &sXh[k & 1][0];
        const unsigned int* Sl = &sXl[k & 1][0];
        bf16x8 bh[4], bl[4];
#pragma unroll
        for (int i = 0; i < 4; ++i) {
            const int t = tw + i * 16 + tsub;
            const int a = tquad * RUNSTRIDE + (t >> 2) * 20 + (t & 3) * 4;
            bh[i] = *(const bf16x8*)(Sh + a);
            bl[i] = *(const bf16x8*)(Sl + a);
        }

        // 48 MFMAs (long latency window hiding the prefetch loads)
#pragma unroll
        for (int mi = 0; mi < 4; ++mi)
#pragma unroll
            for (int ti = 0; ti < 4; ++ti) {
                acc[mi][ti] = __builtin_amdgcn_mfma_f32_16x16x32_bf16(
                    ah[mi], bh[ti], acc[mi][ti], 0, 0, 0);
                acc[mi][ti] = __builtin_amdgcn_mfma_f32_16x16x32_bf16(
                    ah[mi], bl[ti], acc[mi][ti], 0, 0, 0);
                acc[mi][ti] = __builtin_amdgcn_mfma_f32_16x16x32_bf16(
                    al[mi], bh[ti], acc[mi][ti], 0, 0, 0);
            }

        if (k < 9) {
            // pack next x into the other buffer (x vmcnt wait lands here,
            // after the MFMA phase), then one barrier
            packX(xn, &sXh[(k + 1) & 1][0], &sXl[(k + 1) & 1][0]);
            __syncthreads();
#pragma unroll
            for (int mi = 0; mi < 4; ++mi) { ah[mi] = ahn[mi]; al[mi] = aln[mi]; }
        }
    }

    // ---- epilogue: fold scale, store (C/D: col = lane&15, row = quad*4+reg)
#pragma unroll
    for (int mi = 0; mi < 4; ++mi) {
        const int mbase = mw + mi * 16 + tquad * 4;
        const float4 sc = *(const float4*)(sScale + mbase);
        float* op = out + ((size_t)b * M_ + mbase) * T_;
#pragma unroll
        for (int ti = 0; ti < 4; ++ti) {
            const int tg = t0 + tw + ti * 16 + tsub;
            if (tg < T_) {
                op[(size_t)0 * T_ + tg] = acc[mi][ti][0] * sc.x;
                op[(size_t)1 * T_ + tg] = acc[mi][ti][1] * sc.y;
                op[(size_t)2 * T_ + tg] = acc[mi][ti][2] * sc.z;
                op[(size_t)3 * T_ + tg] = acc[mi][ti][3] * sc.w;
            }
        }
    }
}

extern "C" void kernel_launch(void* const* d_in, const int* in_sizes, int n_in,
                              void* d_out, int out_size, void* d_ws, size_t ws_size,
                              hipStream_t stream) {
    const float* x         = (const float*)d_in[0];
    const float* positions = (const float*)d_in[1];
    const float* target    = (const float*)d_in[2];
    const float* w1        = (const float*)d_in[3];
    const float* b1        = (const float*)d_in[4];
    const float* w2        = (const float*)d_in[5];
    const float* b2        = (const float*)d_in[6];
    float* out = (float*)d_out;

    float* scale = (float*)d_ws;                             // B*M floats
    unsigned short* wf = (unsigned short*)(scale + B_ * M_); // 16*81920 u16

    gate_kernel<<<B_ * 32, 320, 0, stream>>>(positions, target, w1, b1, w2, b2,
                                             wf, scale);

    dim3 grid((T_ + 127) / 128, B_);
    merge_gemm<<<grid, 256, 0, stream>>>(x, wf, scale, out);
}